// Round 8
// baseline (687.810 us; speedup 1.0000x reference)
//
#include <hip/hip_runtime.h>

// QuantizedSimpleSSM — round 13: B-operand via scalar pipe. Six rounds show the
// 8x8 LDS-LDS GEMM is pinned at ~50% FMA-issue with both pipes part-busy; the
// b-fragment is wave-uniform if waves own n-strips -> load it with
// s_load_dwordx16 into SGPRs (scalar pipe: no VALU issue, no LDS, no VGPR) and
// let v_fma consume the single allowed SGPR operand. Only X is LDS-staged.
// Per thread-k: 64 fma + 2 ds_read_b32 (vs 64 fma + 6 ds_read_b128).
// Wave-tile: 128t x 32n per wave (acc[2][32]); block 256 thr = 4 waves = 128x128.
// Hazard rails: s_loads + full lgkmcnt(0) wait in asm, "+s" deps tie the wait
// to every FMA (rule 18); a-reads plain C++ (compiler partial lgkm waits are
// over-waiting-safe with extra asm SMEM outstanding); sched_barrier(0) per
// group bounds SGPR pressure (64 b-SGPRs live, < 102). K$ coherence: all W
// inputs written by earlier dispatches. Same staged bits, same fmaf chain per
// output in ascending k, same epilogue ops -> bitwise (absmax 0.0 since R2).
// Pipeline structure from R12 kept: quantBA -> fused(R + quantCD) ->
// fused(recur + D) -> YC.

#define DINX 512
#define LSEQ 512
#define NDIM 512

typedef float sf16 __attribute__((ext_vector_type(16)));

__device__ __forceinline__ float q8(float x) {
    float xa = fabsf(x);
    float w  = __fadd_rn(xa, 1e-8f);
    int e = (int)((__float_as_uint(w) >> 23) & 0xFFu) - 127;   // floor(log2(w))
    e = e < -7 ? -7 : (e > 7 ? 7 : e);
    float p    = __int_as_float((unsigned)((e + 127) << 23));   // exact 2^e
    float invp = __int_as_float((unsigned)((127 - e) << 23));   // exact 2^-e
    float t  = __fmul_rn(__fsub_rn(__fmul_rn(xa, invp), 1.0f), 8.0f);
    float m  = __fmul_rn(rintf(t), 0.125f);                     // half-to-even
    float r  = __fmul_rn(__fadd_rn(1.0f, m), p);
    return copysignf(r, x);
}

// Bqt[c][r] = q8(B[r][c]); block (0,0) also quants A. grid (16,16), block 256.
__global__ __launch_bounds__(256) void quantBA(const float* __restrict__ B,
                                               const float* __restrict__ A,
                                               float* __restrict__ Bqt,
                                               float* __restrict__ Aq) {
    __shared__ float tl[32][33];
    if (blockIdx.x == 0 && blockIdx.y == 0) {
        Aq[threadIdx.x]       = q8(A[threadIdx.x]);
        Aq[256 + threadIdx.x] = q8(A[256 + threadIdx.x]);
    }
    const int r0 = blockIdx.y * 32, c0 = blockIdx.x * 32;
    const int x = threadIdx.x & 31, y = threadIdx.x >> 5;   // 32 x 8
#pragma unroll
    for (int i = 0; i < 32; i += 8)
        tl[y + i][x] = q8(B[(r0 + y + i) * 512 + c0 + x]);
    __syncthreads();
#pragma unroll
    for (int i = 0; i < 32; i += 8)
        Bqt[(c0 + y + i) * 512 + r0 + x] = tl[x][y + i];
}

// Core: acc0[j] (row t0+l) and acc1[j] (row t0+64+l) over n = n0+wv*32+j,
// k strictly ascending 0..511. X,W are [512][512] row-major.
// X LDS-staged 32 rows/tile (R8 staging pattern, X half only); W via SMEM.
__device__ __forceinline__ void gemm_core(const float* __restrict__ X,
                                          const float* __restrict__ W,
                                          int m0, int n0,
                                          float (&acc0)[32], float (&acc1)[32],
                                          float (*Xs)[128], int tid) {
    const int srow = tid >> 4, sseg4 = (tid & 15) * 4;   // staging: 16r x 16c
    const int l = tid & 63;
    const int wv = __builtin_amdgcn_readfirstlane(tid >> 6);   // uniform wave id
    const float* xp = X + (size_t)srow * 512 + m0 + sseg4;
    const float* wp = W + n0 + wv * 32;                  // uniform -> SGPR pair
    for (int k0 = 0; k0 < 512; k0 += 32) {
        float4 x0 = *(const float4*)xp;
        float4 x1 = *(const float4*)(xp + 64);
        float4 x2 = *(const float4*)(xp + 16 * 512);
        float4 x3 = *(const float4*)(xp + 16 * 512 + 64);
        xp += 32 * 512;
        __syncthreads();                 // prev-tile reads done before overwrite
        *(float4*)&Xs[srow][sseg4]           = x0;
        *(float4*)&Xs[srow][64 + sseg4]      = x1;
        *(float4*)&Xs[16 + srow][sseg4]      = x2;
        *(float4*)&Xs[16 + srow][64 + sseg4] = x3;
        __syncthreads();
#pragma unroll
        for (int g = 0; g < 16; ++g) {       // 2 k's per group
            sf16 b0, b1, b2, b3;
            // W[k0+2g][c0 .. c0+31] and W[k0+2g+1][c0 .. c0+31] into SGPRs
            asm volatile("s_load_dwordx16 %0, %1, %2" : "=s"(b0) : "s"(wp), "i"(g * 4096));
            asm volatile("s_load_dwordx16 %0, %1, %2" : "=s"(b1) : "s"(wp), "i"(g * 4096 + 64));
            asm volatile("s_load_dwordx16 %0, %1, %2" : "=s"(b2) : "s"(wp), "i"(g * 4096 + 2048));
            asm volatile("s_load_dwordx16 %0, %1, %2" : "=s"(b3) : "s"(wp), "i"(g * 4096 + 2112));
            float a00 = Xs[2 * g][l];
            float a01 = Xs[2 * g][64 + l];
            float a10 = Xs[2 * g + 1][l];
            float a11 = Xs[2 * g + 1][64 + l];
            asm volatile("s_waitcnt lgkmcnt(0)"
                         : "+s"(b0), "+s"(b1), "+s"(b2), "+s"(b3));
#pragma unroll
            for (int j = 0; j < 16; ++j) {
                acc0[j] = fmaf(a00, b0[j], acc0[j]);
                acc1[j] = fmaf(a01, b0[j], acc1[j]);
            }
#pragma unroll
            for (int j = 0; j < 16; ++j) {
                acc0[16 + j] = fmaf(a00, b1[j], acc0[16 + j]);
                acc1[16 + j] = fmaf(a01, b1[j], acc1[16 + j]);
            }
#pragma unroll
            for (int j = 0; j < 16; ++j) {
                acc0[j] = fmaf(a10, b2[j], acc0[j]);
                acc1[j] = fmaf(a11, b2[j], acc1[j]);
            }
#pragma unroll
            for (int j = 0; j < 16; ++j) {
                acc0[16 + j] = fmaf(a10, b3[j], acc0[16 + j]);
                acc1[16 + j] = fmaf(a11, b3[j], acc1[16 + j]);
            }
            __builtin_amdgcn_sched_barrier(0);   // bound SGPR live ranges
        }
        wp += 32 * 512;
    }
}

// Fused: blocks 0..511 = R-GEMM (R[b][t][n] = sum_d u[b][d][t]*Bqt[d][n]);
// blocks 512..1023 = C/D quant-transpose. grid 1024, block 256, 4/CU.
__global__ __launch_bounds__(256, 4) void fused_RqCD(const float* __restrict__ u,
                                                     const float* __restrict__ Bqt,
                                                     const float* __restrict__ C,
                                                     const float* __restrict__ D,
                                                     float* __restrict__ R,
                                                     float* __restrict__ Cqt,
                                                     float* __restrict__ Dqt) {
    __shared__ float ldsbuf[32 * 128];   // 16 KB
    const int zz = blockIdx.x;
    const int tid = threadIdx.x;
    if (zz < 512) {
        float (*Xs)[128] = (float(*)[128])ldsbuf;
        const int b = zz & 31, t0 = ((zz >> 5) & 3) * 128, n0 = (zz >> 7) * 128;
        const float* ub = u + (size_t)b * (DINX * LSEQ);
        float acc0[32] = {}, acc1[32] = {};
        gemm_core(ub, Bqt, t0, n0, acc0, acc1, Xs, tid);
        const int l = tid & 63;
        const int wv = tid >> 6;
        const int c0 = n0 + wv * 32;
        float* r0 = R + (size_t)b * (LSEQ * NDIM) + (size_t)(t0 + l) * NDIM + c0;
        float* r1 = r0 + (size_t)64 * NDIM;
#pragma unroll
        for (int j4 = 0; j4 < 8; ++j4) {
            *(float4*)(r0 + j4 * 4) = make_float4(acc0[j4 * 4], acc0[j4 * 4 + 1],
                                                  acc0[j4 * 4 + 2], acc0[j4 * 4 + 3]);
            *(float4*)(r1 + j4 * 4) = make_float4(acc1[j4 * 4], acc1[j4 * 4 + 1],
                                                  acc1[j4 * 4 + 2], acc1[j4 * 4 + 3]);
        }
    } else {
        float (*tl)[33] = (float(*)[33])ldsbuf;
        const int d = zz - 512;
        const float* in = (d >> 8) ? D : C;
        float* out      = (d >> 8) ? Dqt : Cqt;
        const int c0 = (d & 15) * 32, r0 = ((d >> 4) & 15) * 32;
        const int x = tid & 31, y = tid >> 5;   // 32 x 8
#pragma unroll
        for (int i = 0; i < 32; i += 8)
            tl[y + i][x] = q8(in[(r0 + y + i) * 512 + c0 + x]);
        __syncthreads();
#pragma unroll
        for (int i = 0; i < 32; i += 8)
            out[(c0 + y + i) * 512 + r0 + x] = tl[x][y + i];
    }
}

// Fused: blocks 0..255 = recurrence (dispatch first -> hidden under D);
// blocks 256..767 = D-GEMM (Pd[b][o][t] = sum_d u[b][d][t]*Dqt[d][o], raw into
// Y scratch). grid 768, block 256, 3/CU.
__global__ __launch_bounds__(256, 3) void fused_Drec(const float* __restrict__ u,
                                                     const float* __restrict__ Dqt,
                                                     const float* __restrict__ R,
                                                     const float* __restrict__ Aq,
                                                     float* __restrict__ Pd,
                                                     float* __restrict__ S) {
    __shared__ float ldsbuf[32 * 128];   // 16 KB
    const int zz = blockIdx.x;
    const int tid = threadIdx.x;
    if (zz >= 256) {
        float (*Xs)[128] = (float(*)[128])ldsbuf;
        const int d = zz - 256;
        const int b = d & 31, t0 = ((d >> 5) & 3) * 128, o0 = (d >> 7) * 128;
        const float* ub = u + (size_t)b * (DINX * LSEQ);
        float acc0[32] = {}, acc1[32] = {};
        gemm_core(ub, Dqt, t0, o0, acc0, acc1, Xs, tid);
        const int l = tid & 63;
        const int wv = tid >> 6;
        const int c0 = o0 + wv * 32;
        float* Yb = Pd + (size_t)b * (NDIM * LSEQ);
#pragma unroll
        for (int j = 0; j < 32; ++j) {
            Yb[(size_t)(c0 + j) * LSEQ + t0 + l]      = acc0[j];
            Yb[(size_t)(c0 + j) * LSEQ + t0 + 64 + l] = acc1[j];
        }
    } else {
        // ---- recurrence (bit-exact chain; tid<64 active, all barrier) ----
        float (*tile)[68] = (float(*)[68])ldsbuf;
        const int b  = zz >> 3;
        const int n0 = (zz & 7) * 64;
        const int n  = tid & 63;
        const bool act = tid < 64;
        float a = 0.0f, s = 0.0f;
        const float* Rb = R + (size_t)b * (LSEQ * NDIM) + n0;
        float* Sb = S + (size_t)b * (NDIM * LSEQ) + (size_t)n0 * LSEQ;
        if (act) a = Aq[n0 + n];
        const int c = (n & 3) * 4;
        const int rbase = n >> 2;                   // 0..15
        for (int t0 = 0; t0 < LSEQ; t0 += 16) {
            if (act) {
#pragma unroll
                for (int tt = 0; tt < 16; ++tt) {
                    float r = Rb[(size_t)(t0 + tt) * NDIM + n];
                    s = q8(__fadd_rn(__fmul_rn(s, a), r));
                    tile[tt][n] = s;
                }
            }
            __syncthreads();
            if (act) {
#pragma unroll
                for (int p = 0; p < 4; ++p) {
                    int row = p * 16 + rbase;
                    float4 v = make_float4(tile[c + 0][row], tile[c + 1][row],
                                           tile[c + 2][row], tile[c + 3][row]);
                    *(float4*)(Sb + (size_t)row * LSEQ + t0 + c) = v;
                }
            }
            __syncthreads();
        }
    }
}

// Y[b][o][t] = q8( (sum_n S[n][t]*Cqt[n][o]) + Pd[b][o][t] ), Pd staged in Y.
// grid 512, block 256.
__global__ __launch_bounds__(256, 2) void gemm_YC(const float* __restrict__ S,
                                                  const float* __restrict__ Cqt,
                                                  float* __restrict__ Y) {
    __shared__ float Xs[32][128];
    const int zz = blockIdx.x;
    const int tid = threadIdx.x;
    const int b = zz & 31, t0 = ((zz >> 5) & 3) * 128, o0 = (zz >> 7) * 128;
    const float* Sb = S + (size_t)b * (NDIM * LSEQ);
    float acc0[32] = {}, acc1[32] = {};
    gemm_core(Sb, Cqt, t0, o0, acc0, acc1, Xs, tid);
    const int l = tid & 63;
    const int wv = tid >> 6;
    const int c0 = o0 + wv * 32;
    float* Yb = Y + (size_t)b * (NDIM * LSEQ);
#pragma unroll
    for (int j = 0; j < 32; ++j) {
        float* p0 = Yb + (size_t)(c0 + j) * LSEQ + t0 + l;
        float* p1 = p0 + 64;
        *p0 = q8(__fadd_rn(acc0[j], *p0));
        *p1 = q8(__fadd_rn(acc1[j], *p1));
    }
}

extern "C" void kernel_launch(void* const* d_in, const int* in_sizes, int n_in,
                              void* d_out, int out_size, void* d_ws, size_t ws_size,
                              hipStream_t stream) {
    const float* u = (const float*)d_in[0];   // (32, 512, 512)
    const float* A = (const float*)d_in[1];   // (512,)
    const float* B = (const float*)d_in[2];   // (512, 512)
    const float* C = (const float*)d_in[3];   // (512, 512)
    const float* D = (const float*)d_in[4];   // (512, 512)

    float* ws  = (float*)d_ws;
    float* Aq  = ws;                    // 512
    float* Bqt = Aq + 512;              // 262144  [d][n]
    float* Cqt = Bqt + 262144;          // 262144  [n][o]
    float* Dqt = Cqt + 262144;          // 262144  [d][o]
    float* R   = Dqt + 262144;          // 8388608 [b][t][n]
    float* S   = R + 8388608;           // 8388608 [b][n][t]
    float* Y   = (float*)d_out;         // 8388608 [b][o][t] (also Pd scratch)

    quantBA<<<dim3(16, 16), 256, 0, stream>>>(B, A, Bqt, Aq);
    fused_RqCD<<<1024, 256, 0, stream>>>(u, Bqt, C, D, R, Cqt, Dqt);
    fused_Drec<<<768, 256, 0, stream>>>(u, Dqt, R, Aq, Y, S);
    gemm_YC<<<512, 256, 0, stream>>>(S, Cqt, Y);
}

// Round 9
// 429.668 us; speedup vs baseline: 1.6008x; 1.6008x over previous
//
#include <hip/hip_runtime.h>

// QuantizedSimpleSSM — round 14: R12 pipeline + 8x16 tiles where wave budget
// permits. R13 (SGPR-B via s_load) falsified: K$ latency serialized the loop
// (122->220us) — reverted. Ledger: DS-pipe ~78% busy is the wall; only
// DS-instr-per-FMA changes moved >5%; 8x16 (DS:VALU 1.125 vs 1.5) measured
// 100us/GEMM (R11) vs ~115 at 8x8. This round: D-pass and YC -> 8x16
// (gemm_pass16, spill-proofed BK=16/unroll-2, VGPR 84 in R11); R-pass stays
// 8x8 (its 8x16 form would drain to 1 wave/SIMD after quant blocks retire).
// All chains/epilogues verbatim from bitwise-validated rounds -> absmax 0.0.
// Numerics contract (absmax 0.0 since R2): every output element is one fp32
// FMA chain in strictly ascending k; recurrence mul-then-add + q8.

#define DINX 512
#define LSEQ 512
#define NDIM 512

__device__ __forceinline__ float q8(float x) {
    float xa = fabsf(x);
    float w  = __fadd_rn(xa, 1e-8f);
    int e = (int)((__float_as_uint(w) >> 23) & 0xFFu) - 127;   // floor(log2(w))
    e = e < -7 ? -7 : (e > 7 ? 7 : e);
    float p    = __int_as_float((unsigned)((e + 127) << 23));   // exact 2^e
    float invp = __int_as_float((unsigned)((127 - e) << 23));   // exact 2^-e
    float t  = __fmul_rn(__fsub_rn(__fmul_rn(xa, invp), 1.0f), 8.0f);
    float m  = __fmul_rn(rintf(t), 0.125f);                     // half-to-even
    float r  = __fmul_rn(__fadd_rn(1.0f, m), p);
    return copysignf(r, x);
}

// Bqt[c][r] = q8(B[r][c]); block (0,0) also quants A. grid (16,16), block 256.
__global__ __launch_bounds__(256) void quantBA(const float* __restrict__ B,
                                               const float* __restrict__ A,
                                               float* __restrict__ Bqt,
                                               float* __restrict__ Aq) {
    __shared__ float tl[32][33];
    if (blockIdx.x == 0 && blockIdx.y == 0) {
        Aq[threadIdx.x]       = q8(A[threadIdx.x]);
        Aq[256 + threadIdx.x] = q8(A[256 + threadIdx.x]);
    }
    const int r0 = blockIdx.y * 32, c0 = blockIdx.x * 32;
    const int x = threadIdx.x & 31, y = threadIdx.x >> 5;   // 32 x 8
#pragma unroll
    for (int i = 0; i < 32; i += 8)
        tl[y + i][x] = q8(B[(r0 + y + i) * 512 + c0 + x]);
    __syncthreads();
#pragma unroll
    for (int i = 0; i < 32; i += 8)
        Bqt[(c0 + y + i) * 512 + r0 + x] = tl[x][y + i];
}

// ---------- 8x8 per-thread tile (R8 bit-exact path, used by R-GEMM) ----------
// acc[p][i][q][j] += sum_k X[k][m0 + p*64 + tx*4 + i] * W[k][n0 + q*64 + ty*4 + j]
// k strictly ascending. LDS Xs/Ws [32][128], BK=32 per barrier pair.
__device__ __forceinline__ void gemm_pass(const float* __restrict__ X,
                                          const float* __restrict__ W,
                                          int m0, int n0, int KTOT,
                                          float (&acc)[2][4][2][4],
                                          float (*Xs)[128], float (*Ws)[128],
                                          int tid) {
    const int tx = tid & 15, ty = tid >> 4;
    const int srow = tid >> 4, sseg4 = (tid & 15) * 4;   // 16 rows x 16 chunks
    const float* xp = X + (size_t)srow * 512 + m0 + sseg4;
    const float* wp = W + (size_t)srow * 512 + n0 + sseg4;
    for (int k0 = 0; k0 < KTOT; k0 += 32) {
        float4 x0 = *(const float4*)xp;
        float4 x1 = *(const float4*)(xp + 64);
        float4 x2 = *(const float4*)(xp + 16 * 512);
        float4 x3 = *(const float4*)(xp + 16 * 512 + 64);
        float4 w0 = *(const float4*)wp;
        float4 w1 = *(const float4*)(wp + 64);
        float4 w2 = *(const float4*)(wp + 16 * 512);
        float4 w3 = *(const float4*)(wp + 16 * 512 + 64);
        xp += 32 * 512; wp += 32 * 512;
        __syncthreads();                 // prev-tile reads done before overwrite
        *(float4*)&Xs[srow][sseg4]           = x0;
        *(float4*)&Xs[srow][64 + sseg4]      = x1;
        *(float4*)&Xs[16 + srow][sseg4]      = x2;
        *(float4*)&Xs[16 + srow][64 + sseg4] = x3;
        *(float4*)&Ws[srow][sseg4]           = w0;
        *(float4*)&Ws[srow][64 + sseg4]      = w1;
        *(float4*)&Ws[16 + srow][sseg4]      = w2;
        *(float4*)&Ws[16 + srow][64 + sseg4] = w3;
        __syncthreads();
#pragma unroll
        for (int k = 0; k < 32; ++k) {
            float a[2][4], b[2][4];
            *(float4*)&a[0][0] = *(const float4*)&Xs[k][tx * 4];
            *(float4*)&a[1][0] = *(const float4*)&Xs[k][64 + tx * 4];
            *(float4*)&b[0][0] = *(const float4*)&Ws[k][ty * 4];
            *(float4*)&b[1][0] = *(const float4*)&Ws[k][64 + ty * 4];
#pragma unroll
            for (int p = 0; p < 2; ++p)
#pragma unroll
                for (int i = 0; i < 4; ++i)
#pragma unroll
                    for (int q = 0; q < 2; ++q)
#pragma unroll
                        for (int j = 0; j < 4; ++j)
                            acc[p][i][q][j] = fmaf(a[p][i], b[q][j], acc[p][i][q][j]);
        }
    }
}

// ---------- 8x16 per-thread tile (R11 bit-exact, BK=16, unroll-2) ----------
// acc[p][i][q][j] += sum_k X[k][m0 + p*64 + tx*4 + i] * W[k][n0 + q*64 + ty*4 + j]
// with q in 0..3 (256-wide n-tile), k strictly ascending.
// LDS: Xs[16][128] (8KB) + Ws[16][256] (16KB), single-buffered.
__device__ __forceinline__ void gemm_pass16(const float* __restrict__ X,
                                            const float* __restrict__ W,
                                            int m0, int n0, int KTOT,
                                            float (&acc)[2][4][4][4],
                                            float (*Xs)[128], float (*Ws)[256],
                                            int tid) {
    const int tx = tid & 15, ty = tid >> 4;              // 16 x 16 thread grid
    const int srow = tid >> 4, sseg4 = (tid & 15) * 4;   // X staging: 16r x 16c
    const int wrow = tid >> 6, wseg4 = (tid & 63) * 4;   // W staging: 4r x 64c
    const float* xp = X + (size_t)srow * 512 + m0 + sseg4;
    const float* wp = W + (size_t)wrow * 512 + n0 + wseg4;
    for (int k0 = 0; k0 < KTOT; k0 += 16) {
        float4 x0 = *(const float4*)xp;
        float4 x1 = *(const float4*)(xp + 64);
        float4 w0 = *(const float4*)wp;
        float4 w1 = *(const float4*)(wp + 4 * 512);
        float4 w2 = *(const float4*)(wp + 8 * 512);
        float4 w3 = *(const float4*)(wp + 12 * 512);
        xp += 16 * 512; wp += 16 * 512;
        __syncthreads();                 // prev-tile reads done before overwrite
        *(float4*)&Xs[srow][sseg4]       = x0;
        *(float4*)&Xs[srow][64 + sseg4]  = x1;
        *(float4*)&Ws[wrow][wseg4]       = w0;
        *(float4*)&Ws[4 + wrow][wseg4]   = w1;
        *(float4*)&Ws[8 + wrow][wseg4]   = w2;
        *(float4*)&Ws[12 + wrow][wseg4]  = w3;
        __syncthreads();
#pragma unroll 2
        for (int k = 0; k < 16; ++k) {
            float a[2][4], b[4][4];
            *(float4*)&a[0][0] = *(const float4*)&Xs[k][tx * 4];
            *(float4*)&a[1][0] = *(const float4*)&Xs[k][64 + tx * 4];
#pragma unroll
            for (int q = 0; q < 4; ++q)
                *(float4*)&b[q][0] = *(const float4*)&Ws[k][q * 64 + ty * 4];
#pragma unroll
            for (int p = 0; p < 2; ++p)
#pragma unroll
                for (int i = 0; i < 4; ++i)
#pragma unroll
                    for (int q = 0; q < 4; ++q)
#pragma unroll
                        for (int j = 0; j < 4; ++j)
                            acc[p][i][q][j] = fmaf(a[p][i], b[q][j], acc[p][i][q][j]);
        }
    }
}

// Fused: blocks 0..511 = R-GEMM (8x8); blocks 512..1023 = C/D quant-transpose.
// grid 1024, block 256, 4/CU. (Proven 122us in R12.)
__global__ __launch_bounds__(256, 4) void fused_RqCD(const float* __restrict__ u,
                                                     const float* __restrict__ Bqt,
                                                     const float* __restrict__ C,
                                                     const float* __restrict__ D,
                                                     float* __restrict__ R,
                                                     float* __restrict__ Cqt,
                                                     float* __restrict__ Dqt) {
    __shared__ float ldsbuf[2 * 32 * 128];   // 32 KB
    const int zz = blockIdx.x;
    const int tid = threadIdx.x;
    if (zz < 512) {
        float (*Xs)[128] = (float(*)[128])ldsbuf;
        float (*Ws)[128] = (float(*)[128])(ldsbuf + 32 * 128);
        const int b = zz & 31, t0 = ((zz >> 5) & 3) * 128, n0 = (zz >> 7) * 128;
        const int tx = tid & 15, ty = tid >> 4;
        const float* ub = u + (size_t)b * (DINX * LSEQ);
        float acc[2][4][2][4] = {};
        gemm_pass(ub, Bqt, t0, n0, DINX, acc, Xs, Ws, tid);
        float* Rb = R + (size_t)b * (LSEQ * NDIM);
#pragma unroll
        for (int p = 0; p < 2; ++p)
#pragma unroll
            for (int i = 0; i < 4; ++i) {
                float* row = Rb + (size_t)(t0 + p * 64 + tx * 4 + i) * NDIM + n0;
                *(float4*)(row + ty * 4)      = make_float4(acc[p][i][0][0], acc[p][i][0][1],
                                                            acc[p][i][0][2], acc[p][i][0][3]);
                *(float4*)(row + 64 + ty * 4) = make_float4(acc[p][i][1][0], acc[p][i][1][1],
                                                            acc[p][i][1][2], acc[p][i][1][3]);
            }
    } else {
        float (*tl)[33] = (float(*)[33])ldsbuf;
        const int d = zz - 512;
        const float* in = (d >> 8) ? D : C;
        float* out      = (d >> 8) ? Dqt : Cqt;
        const int c0 = (d & 15) * 32, r0 = ((d >> 4) & 15) * 32;
        const int x = tid & 31, y = tid >> 5;   // 32 x 8
#pragma unroll
        for (int i = 0; i < 32; i += 8)
            tl[y + i][x] = q8(in[(r0 + y + i) * 512 + c0 + x]);
        __syncthreads();
#pragma unroll
        for (int i = 0; i < 32; i += 8)
            out[(c0 + y + i) * 512 + r0 + x] = tl[x][y + i];
    }
}

// Fused: blocks 0..255 = recurrence (dispatch first); blocks 256..511 = D-GEMM
// at 8x16 (Pd[b][o][t] = sum_d u[b][d][t]*Dqt[d][o], raw into Y scratch).
// grid 512, block 256, 2/CU -> ~1 recur + 1 D block per CU.
__global__ __launch_bounds__(256, 2) void fused_Drec(const float* __restrict__ u,
                                                     const float* __restrict__ Dqt,
                                                     const float* __restrict__ R,
                                                     const float* __restrict__ Aq,
                                                     float* __restrict__ Pd,
                                                     float* __restrict__ S) {
    __shared__ float ldsbuf[16 * 128 + 16 * 256];   // 24 KB
    const int zz = blockIdx.x;
    const int tid = threadIdx.x;
    if (zz >= 256) {
        // ---- D-GEMM, 8x16 (R11 bit-exact core + epilogue) ----
        float (*Xs)[128] = (float(*)[128])ldsbuf;
        float (*Ws)[256] = (float(*)[256])(ldsbuf + 16 * 128);
        const int d = zz - 256;
        const int b = d & 31, t0 = ((d >> 5) & 3) * 128, n0 = (d >> 7) * 256;
        const int tx = tid & 15, ty = tid >> 4;
        const float* ub = u + (size_t)b * (DINX * LSEQ);
        float acc[2][4][4][4] = {};
        gemm_pass16(ub, Dqt, t0, n0, DINX, acc, Xs, Ws, tid);
        float* Yb = Pd + (size_t)b * (NDIM * LSEQ);
#pragma unroll
        for (int q = 0; q < 4; ++q)
#pragma unroll
            for (int j = 0; j < 4; ++j) {
                float* row = Yb + (size_t)(n0 + q * 64 + ty * 4 + j) * LSEQ + t0;
                *(float4*)(row + tx * 4)      = make_float4(acc[0][0][q][j], acc[0][1][q][j],
                                                            acc[0][2][q][j], acc[0][3][q][j]);
                *(float4*)(row + 64 + tx * 4) = make_float4(acc[1][0][q][j], acc[1][1][q][j],
                                                            acc[1][2][q][j], acc[1][3][q][j]);
            }
    } else {
        // ---- recurrence (bit-exact chain; tid<64 active, all barrier) ----
        float (*tile)[68] = (float(*)[68])ldsbuf;
        const int b  = zz >> 3;
        const int n0 = (zz & 7) * 64;
        const int n  = tid & 63;
        const bool act = tid < 64;
        float a = 0.0f, s = 0.0f;
        const float* Rb = R + (size_t)b * (LSEQ * NDIM) + n0;
        float* Sb = S + (size_t)b * (NDIM * LSEQ) + (size_t)n0 * LSEQ;
        if (act) a = Aq[n0 + n];
        const int c = (n & 3) * 4;
        const int rbase = n >> 2;                   // 0..15
        for (int t0 = 0; t0 < LSEQ; t0 += 16) {
            if (act) {
#pragma unroll
                for (int tt = 0; tt < 16; ++tt) {
                    float r = Rb[(size_t)(t0 + tt) * NDIM + n];
                    s = q8(__fadd_rn(__fmul_rn(s, a), r));
                    tile[tt][n] = s;
                }
            }
            __syncthreads();
            if (act) {
#pragma unroll
                for (int p = 0; p < 4; ++p) {
                    int row = p * 16 + rbase;
                    float4 v = make_float4(tile[c + 0][row], tile[c + 1][row],
                                           tile[c + 2][row], tile[c + 3][row]);
                    *(float4*)(Sb + (size_t)row * LSEQ + t0 + c) = v;
                }
            }
            __syncthreads();
        }
    }
}

// Y[b][o][t] = q8( (sum_n S[n][t]*Cqt[n][o]) + Pd[b][o][t] ), Pd staged in Y.
// 8x16 tile (R10 bit-exact epilogue). grid 256, block 256.
__global__ __launch_bounds__(256, 2) void gemm_YC(const float* __restrict__ S,
                                                  const float* __restrict__ Cqt,
                                                  float* __restrict__ Y) {
    __shared__ float Xs[16][128];
    __shared__ float Ws[16][256];
    const int zz = blockIdx.x;
    const int tid = threadIdx.x;
    const int b = zz & 31, t0 = ((zz >> 5) & 3) * 128, o0 = (zz >> 7) * 256;
    const int tx = tid & 15, ty = tid >> 4;
    const float* Sb = S + (size_t)b * (NDIM * LSEQ);
    float acc[2][4][4][4] = {};
    gemm_pass16(Sb, Cqt, t0, o0, NDIM, acc, Xs, Ws, tid);

    float* Yb = Y + (size_t)b * (NDIM * LSEQ);
#pragma unroll
    for (int q = 0; q < 4; ++q)
#pragma unroll
        for (int j = 0; j < 4; ++j) {
            float* row = Yb + (size_t)(o0 + q * 64 + ty * 4 + j) * LSEQ + t0;
            float4 v0 = *(const float4*)(row + tx * 4);
            float4 v1 = *(const float4*)(row + 64 + tx * 4);
            *(float4*)(row + tx * 4) =
                make_float4(q8(__fadd_rn(acc[0][0][q][j], v0.x)),
                            q8(__fadd_rn(acc[0][1][q][j], v0.y)),
                            q8(__fadd_rn(acc[0][2][q][j], v0.z)),
                            q8(__fadd_rn(acc[0][3][q][j], v0.w)));
            *(float4*)(row + 64 + tx * 4) =
                make_float4(q8(__fadd_rn(acc[1][0][q][j], v1.x)),
                            q8(__fadd_rn(acc[1][1][q][j], v1.y)),
                            q8(__fadd_rn(acc[1][2][q][j], v1.z)),
                            q8(__fadd_rn(acc[1][3][q][j], v1.w)));
        }
}

extern "C" void kernel_launch(void* const* d_in, const int* in_sizes, int n_in,
                              void* d_out, int out_size, void* d_ws, size_t ws_size,
                              hipStream_t stream) {
    const float* u = (const float*)d_in[0];   // (32, 512, 512)
    const float* A = (const float*)d_in[1];   // (512,)
    const float* B = (const float*)d_in[2];   // (512, 512)
    const float* C = (const float*)d_in[3];   // (512, 512)
    const float* D = (const float*)d_in[4];   // (512, 512)

    float* ws  = (float*)d_ws;
    float* Aq  = ws;                    // 512
    float* Bqt = Aq + 512;              // 262144  [d][n]
    float* Cqt = Bqt + 262144;          // 262144  [n][o]
    float* Dqt = Cqt + 262144;          // 262144  [d][o]
    float* R   = Dqt + 262144;          // 8388608 [b][t][n]
    float* S   = R + 8388608;           // 8388608 [b][n][t]
    float* Y   = (float*)d_out;         // 8388608 [b][o][t] (also Pd scratch)

    quantBA<<<dim3(16, 16), 256, 0, stream>>>(B, A, Bqt, Aq);
    fused_RqCD<<<1024, 256, 0, stream>>>(u, Bqt, C, D, R, Cqt, Dqt);
    fused_Drec<<<512, 256, 0, stream>>>(u, Dqt, R, Aq, Y, S);
    gemm_YC<<<256, 256, 0, stream>>>(S, Cqt, Y);
}

// Round 10
// 388.677 us; speedup vs baseline: 1.7696x; 1.1055x over previous
//
#include <hip/hip_runtime.h>

// QuantizedSimpleSSM — round 15: R12 pipeline (best, 370us) + double-buffered
// 8x8 GEMM for the D-pass and YC only. R14 falsified 8x16-at-low-occupancy
// (148/145us, pre-registered signature) -> reverted to R12 shapes. Remaining
// non-DS time per GEMM ~18us = barrier drains + issue gaps; dbuf (one barrier
// per BK=32 tile, loads in flight across compute) targets it. R6/R10 dbuf
// failures were register blowup from full unroll; fix = #pragma unroll 2 on
// the compute loop (R11-proven anti-spill). Budget: acc 64 + staging 32 +
// frags 12 + addr 14 ~ 140 < 256 cap (launch_bounds(256,2)), LDS 64KB ->
// 2 blocks/CU. fused_RqCD kept R12-verbatim (proven 122us). Same tiles, same
// ascending-k FMA chains, same staged bits -> bitwise (absmax 0.0 since R2).
// Numerics contract: every output element is one fp32 FMA chain in strictly
// ascending k; recurrence mul-then-add + q8.

#define DINX 512
#define LSEQ 512
#define NDIM 512

__device__ __forceinline__ float q8(float x) {
    float xa = fabsf(x);
    float w  = __fadd_rn(xa, 1e-8f);
    int e = (int)((__float_as_uint(w) >> 23) & 0xFFu) - 127;   // floor(log2(w))
    e = e < -7 ? -7 : (e > 7 ? 7 : e);
    float p    = __int_as_float((unsigned)((e + 127) << 23));   // exact 2^e
    float invp = __int_as_float((unsigned)((127 - e) << 23));   // exact 2^-e
    float t  = __fmul_rn(__fsub_rn(__fmul_rn(xa, invp), 1.0f), 8.0f);
    float m  = __fmul_rn(rintf(t), 0.125f);                     // half-to-even
    float r  = __fmul_rn(__fadd_rn(1.0f, m), p);
    return copysignf(r, x);
}

// Bqt[c][r] = q8(B[r][c]); block (0,0) also quants A. grid (16,16), block 256.
__global__ __launch_bounds__(256) void quantBA(const float* __restrict__ B,
                                               const float* __restrict__ A,
                                               float* __restrict__ Bqt,
                                               float* __restrict__ Aq) {
    __shared__ float tl[32][33];
    if (blockIdx.x == 0 && blockIdx.y == 0) {
        Aq[threadIdx.x]       = q8(A[threadIdx.x]);
        Aq[256 + threadIdx.x] = q8(A[256 + threadIdx.x]);
    }
    const int r0 = blockIdx.y * 32, c0 = blockIdx.x * 32;
    const int x = threadIdx.x & 31, y = threadIdx.x >> 5;   // 32 x 8
#pragma unroll
    for (int i = 0; i < 32; i += 8)
        tl[y + i][x] = q8(B[(r0 + y + i) * 512 + c0 + x]);
    __syncthreads();
#pragma unroll
    for (int i = 0; i < 32; i += 8)
        Bqt[(c0 + y + i) * 512 + r0 + x] = tl[x][y + i];
}

// ---------- 8x8 single-buffer (R8 bit-exact, used by R-GEMM) ----------
__device__ __forceinline__ void gemm_pass(const float* __restrict__ X,
                                          const float* __restrict__ W,
                                          int m0, int n0, int KTOT,
                                          float (&acc)[2][4][2][4],
                                          float (*Xs)[128], float (*Ws)[128],
                                          int tid) {
    const int tx = tid & 15, ty = tid >> 4;
    const int srow = tid >> 4, sseg4 = (tid & 15) * 4;   // 16 rows x 16 chunks
    const float* xp = X + (size_t)srow * 512 + m0 + sseg4;
    const float* wp = W + (size_t)srow * 512 + n0 + sseg4;
    for (int k0 = 0; k0 < KTOT; k0 += 32) {
        float4 x0 = *(const float4*)xp;
        float4 x1 = *(const float4*)(xp + 64);
        float4 x2 = *(const float4*)(xp + 16 * 512);
        float4 x3 = *(const float4*)(xp + 16 * 512 + 64);
        float4 w0 = *(const float4*)wp;
        float4 w1 = *(const float4*)(wp + 64);
        float4 w2 = *(const float4*)(wp + 16 * 512);
        float4 w3 = *(const float4*)(wp + 16 * 512 + 64);
        xp += 32 * 512; wp += 32 * 512;
        __syncthreads();                 // prev-tile reads done before overwrite
        *(float4*)&Xs[srow][sseg4]           = x0;
        *(float4*)&Xs[srow][64 + sseg4]      = x1;
        *(float4*)&Xs[16 + srow][sseg4]      = x2;
        *(float4*)&Xs[16 + srow][64 + sseg4] = x3;
        *(float4*)&Ws[srow][sseg4]           = w0;
        *(float4*)&Ws[srow][64 + sseg4]      = w1;
        *(float4*)&Ws[16 + srow][sseg4]      = w2;
        *(float4*)&Ws[16 + srow][64 + sseg4] = w3;
        __syncthreads();
#pragma unroll
        for (int k = 0; k < 32; ++k) {
            float a[2][4], b[2][4];
            *(float4*)&a[0][0] = *(const float4*)&Xs[k][tx * 4];
            *(float4*)&a[1][0] = *(const float4*)&Xs[k][64 + tx * 4];
            *(float4*)&b[0][0] = *(const float4*)&Ws[k][ty * 4];
            *(float4*)&b[1][0] = *(const float4*)&Ws[k][64 + ty * 4];
#pragma unroll
            for (int p = 0; p < 2; ++p)
#pragma unroll
                for (int i = 0; i < 4; ++i)
#pragma unroll
                    for (int q = 0; q < 2; ++q)
#pragma unroll
                        for (int j = 0; j < 4; ++j)
                            acc[p][i][q][j] = fmaf(a[p][i], b[q][j], acc[p][i][q][j]);
        }
    }
}

// 32-k compute block at LDS row offset `base` (unroll-2 caps live registers).
__device__ __forceinline__ void compute32(const float (*Xs)[128], const float (*Ws)[128],
                                          int base, int tx, int ty,
                                          float (&acc)[2][4][2][4]) {
#pragma unroll 2
    for (int k = 0; k < 32; ++k) {
        float a[2][4], b[2][4];
        *(float4*)&a[0][0] = *(const float4*)&Xs[base + k][tx * 4];
        *(float4*)&a[1][0] = *(const float4*)&Xs[base + k][64 + tx * 4];
        *(float4*)&b[0][0] = *(const float4*)&Ws[base + k][ty * 4];
        *(float4*)&b[1][0] = *(const float4*)&Ws[base + k][64 + ty * 4];
#pragma unroll
        for (int p = 0; p < 2; ++p)
#pragma unroll
            for (int i = 0; i < 4; ++i)
#pragma unroll
                for (int q = 0; q < 2; ++q)
#pragma unroll
                    for (int j = 0; j < 4; ++j)
                        acc[p][i][q][j] = fmaf(a[p][i], b[q][j], acc[p][i][q][j]);
    }
}

// ---------- 8x8 double-buffered (D-GEMM, YC). Xs/Ws are [64][128]: rows
// (it&1)*32..+31 hold tile it. One barrier per tile; next tile's loads are
// issued BEFORE compute so HBM/L2 latency hides under the 2048 FMAs.
// Same FMA chain order as gemm_pass -> bitwise identical.
__device__ __forceinline__ void gemm_pass_db(const float* __restrict__ X,
                                             const float* __restrict__ W,
                                             int m0, int n0, int KTOT,
                                             float (&acc)[2][4][2][4],
                                             float (*Xs)[128], float (*Ws)[128],
                                             int tid) {
    const int tx = tid & 15, ty = tid >> 4;
    const int srow = tid >> 4, sseg4 = (tid & 15) * 4;
    const float* xp = X + (size_t)srow * 512 + m0 + sseg4;
    const float* wp = W + (size_t)srow * 512 + n0 + sseg4;
    // prologue: tile 0 -> buffer rows 0..31
    {
        float4 x0 = *(const float4*)xp;
        float4 x1 = *(const float4*)(xp + 64);
        float4 x2 = *(const float4*)(xp + 16 * 512);
        float4 x3 = *(const float4*)(xp + 16 * 512 + 64);
        float4 w0 = *(const float4*)wp;
        float4 w1 = *(const float4*)(wp + 64);
        float4 w2 = *(const float4*)(wp + 16 * 512);
        float4 w3 = *(const float4*)(wp + 16 * 512 + 64);
        xp += 32 * 512; wp += 32 * 512;
        *(float4*)&Xs[srow][sseg4]           = x0;
        *(float4*)&Xs[srow][64 + sseg4]      = x1;
        *(float4*)&Xs[16 + srow][sseg4]      = x2;
        *(float4*)&Xs[16 + srow][64 + sseg4] = x3;
        *(float4*)&Ws[srow][sseg4]           = w0;
        *(float4*)&Ws[srow][64 + sseg4]      = w1;
        *(float4*)&Ws[16 + srow][sseg4]      = w2;
        *(float4*)&Ws[16 + srow][64 + sseg4] = w3;
        __syncthreads();
    }
    const int NT = KTOT >> 5;
    for (int it = 0; it < NT - 1; ++it) {
        const int cb = (it & 1) << 5;
        const int nb = cb ^ 32;
        // issue next tile's loads; they stay in flight across compute32
        float4 x0 = *(const float4*)xp;
        float4 x1 = *(const float4*)(xp + 64);
        float4 x2 = *(const float4*)(xp + 16 * 512);
        float4 x3 = *(const float4*)(xp + 16 * 512 + 64);
        float4 w0 = *(const float4*)wp;
        float4 w1 = *(const float4*)(wp + 64);
        float4 w2 = *(const float4*)(wp + 16 * 512);
        float4 w3 = *(const float4*)(wp + 16 * 512 + 64);
        xp += 32 * 512; wp += 32 * 512;
        compute32(Xs, Ws, cb, tx, ty, acc);
        // other buffer: nobody reads it until after the barrier below
        *(float4*)&Xs[nb + srow][sseg4]           = x0;
        *(float4*)&Xs[nb + srow][64 + sseg4]      = x1;
        *(float4*)&Xs[nb + 16 + srow][sseg4]      = x2;
        *(float4*)&Xs[nb + 16 + srow][64 + sseg4] = x3;
        *(float4*)&Ws[nb + srow][sseg4]           = w0;
        *(float4*)&Ws[nb + srow][64 + sseg4]      = w1;
        *(float4*)&Ws[nb + 16 + srow][sseg4]      = w2;
        *(float4*)&Ws[nb + 16 + srow][64 + sseg4] = w3;
        __syncthreads();                 // nb ready; cb reads all done
    }
    compute32(Xs, Ws, ((NT - 1) & 1) << 5, tx, ty, acc);
}

// Fused: blocks 0..511 = R-GEMM (8x8 single-buf); blocks 512..1023 = C/D
// quant-transpose. grid 1024, block 256, 4/CU. (R12-verbatim, proven 122us.)
__global__ __launch_bounds__(256, 4) void fused_RqCD(const float* __restrict__ u,
                                                     const float* __restrict__ Bqt,
                                                     const float* __restrict__ C,
                                                     const float* __restrict__ D,
                                                     float* __restrict__ R,
                                                     float* __restrict__ Cqt,
                                                     float* __restrict__ Dqt) {
    __shared__ float ldsbuf[2 * 32 * 128];   // 32 KB
    const int zz = blockIdx.x;
    const int tid = threadIdx.x;
    if (zz < 512) {
        float (*Xs)[128] = (float(*)[128])ldsbuf;
        float (*Ws)[128] = (float(*)[128])(ldsbuf + 32 * 128);
        const int b = zz & 31, t0 = ((zz >> 5) & 3) * 128, n0 = (zz >> 7) * 128;
        const int tx = tid & 15, ty = tid >> 4;
        const float* ub = u + (size_t)b * (DINX * LSEQ);
        float acc[2][4][2][4] = {};
        gemm_pass(ub, Bqt, t0, n0, DINX, acc, Xs, Ws, tid);
        float* Rb = R + (size_t)b * (LSEQ * NDIM);
#pragma unroll
        for (int p = 0; p < 2; ++p)
#pragma unroll
            for (int i = 0; i < 4; ++i) {
                float* row = Rb + (size_t)(t0 + p * 64 + tx * 4 + i) * NDIM + n0;
                *(float4*)(row + ty * 4)      = make_float4(acc[p][i][0][0], acc[p][i][0][1],
                                                            acc[p][i][0][2], acc[p][i][0][3]);
                *(float4*)(row + 64 + ty * 4) = make_float4(acc[p][i][1][0], acc[p][i][1][1],
                                                            acc[p][i][1][2], acc[p][i][1][3]);
            }
    } else {
        float (*tl)[33] = (float(*)[33])ldsbuf;
        const int d = zz - 512;
        const float* in = (d >> 8) ? D : C;
        float* out      = (d >> 8) ? Dqt : Cqt;
        const int c0 = (d & 15) * 32, r0 = ((d >> 4) & 15) * 32;
        const int x = tid & 31, y = tid >> 5;   // 32 x 8
#pragma unroll
        for (int i = 0; i < 32; i += 8)
            tl[y + i][x] = q8(in[(r0 + y + i) * 512 + c0 + x]);
        __syncthreads();
#pragma unroll
        for (int i = 0; i < 32; i += 8)
            out[(c0 + y + i) * 512 + r0 + x] = tl[x][y + i];
    }
}

// Fused: blocks 0..255 = recurrence (dispatch first -> hidden under D);
// blocks 256..767 = D-GEMM 8x8 double-buffered (Pd raw into Y scratch).
// grid 768, block 256, LDS 64KB -> 2 blocks/CU.
__global__ __launch_bounds__(256, 2) void fused_Drec(const float* __restrict__ u,
                                                     const float* __restrict__ Dqt,
                                                     const float* __restrict__ R,
                                                     const float* __restrict__ Aq,
                                                     float* __restrict__ Pd,
                                                     float* __restrict__ S) {
    __shared__ float ldsbuf[2 * 64 * 128];   // 64 KB
    const int zz = blockIdx.x;
    const int tid = threadIdx.x;
    if (zz >= 256) {
        float (*Xs)[128] = (float(*)[128])ldsbuf;
        float (*Ws)[128] = (float(*)[128])(ldsbuf + 64 * 128);
        const int d = zz - 256;
        const int b = d & 31, t0 = ((d >> 5) & 3) * 128, o0 = (d >> 7) * 128;
        const int tx = tid & 15, ty = tid >> 4;
        const float* ub = u + (size_t)b * (DINX * LSEQ);
        float acc[2][4][2][4] = {};
        gemm_pass_db(ub, Dqt, t0, o0, DINX, acc, Xs, Ws, tid);
        float* Yb = Pd + (size_t)b * (NDIM * LSEQ);
#pragma unroll
        for (int q = 0; q < 2; ++q)
#pragma unroll
            for (int j = 0; j < 4; ++j) {
                float* row = Yb + (size_t)(o0 + q * 64 + ty * 4 + j) * LSEQ + t0;
                *(float4*)(row + tx * 4)      = make_float4(acc[0][0][q][j], acc[0][1][q][j],
                                                            acc[0][2][q][j], acc[0][3][q][j]);
                *(float4*)(row + 64 + tx * 4) = make_float4(acc[1][0][q][j], acc[1][1][q][j],
                                                            acc[1][2][q][j], acc[1][3][q][j]);
            }
    } else {
        // ---- recurrence (bit-exact chain; tid<64 active, all barrier) ----
        float (*tile)[68] = (float(*)[68])ldsbuf;
        const int b  = zz >> 3;
        const int n0 = (zz & 7) * 64;
        const int n  = tid & 63;
        const bool act = tid < 64;
        float a = 0.0f, s = 0.0f;
        const float* Rb = R + (size_t)b * (LSEQ * NDIM) + n0;
        float* Sb = S + (size_t)b * (NDIM * LSEQ) + (size_t)n0 * LSEQ;
        if (act) a = Aq[n0 + n];
        const int c = (n & 3) * 4;
        const int rbase = n >> 2;                   // 0..15
        for (int t0 = 0; t0 < LSEQ; t0 += 16) {
            if (act) {
#pragma unroll
                for (int tt = 0; tt < 16; ++tt) {
                    float r = Rb[(size_t)(t0 + tt) * NDIM + n];
                    s = q8(__fadd_rn(__fmul_rn(s, a), r));
                    tile[tt][n] = s;
                }
            }
            __syncthreads();
            if (act) {
#pragma unroll
                for (int p = 0; p < 4; ++p) {
                    int row = p * 16 + rbase;
                    float4 v = make_float4(tile[c + 0][row], tile[c + 1][row],
                                           tile[c + 2][row], tile[c + 3][row]);
                    *(float4*)(Sb + (size_t)row * LSEQ + t0 + c) = v;
                }
            }
            __syncthreads();
        }
    }
}

// Y[b][o][t] = q8( (sum_n S[n][t]*Cqt[n][o]) + Pd[b][o][t] ), Pd staged in Y.
// 8x8 double-buffered. grid (4,4,32), block 256, 2 blocks/CU.
__global__ __launch_bounds__(256, 2) void gemm_YC(const float* __restrict__ S,
                                                  const float* __restrict__ Cqt,
                                                  float* __restrict__ Y) {
    __shared__ float Xs[64][128];
    __shared__ float Ws[64][128];
    const int b  = blockIdx.z;
    const int t0 = blockIdx.x * 128, o0 = blockIdx.y * 128;
    const int tid = threadIdx.x;
    const int tx = tid & 15, ty = tid >> 4;
    const float* Sb = S + (size_t)b * (NDIM * LSEQ);
    float acc[2][4][2][4] = {};
    gemm_pass_db(Sb, Cqt, t0, o0, NDIM, acc, Xs, Ws, tid);

    float* Yb = Y + (size_t)b * (NDIM * LSEQ);
#pragma unroll
    for (int q = 0; q < 2; ++q)
#pragma unroll
        for (int j = 0; j < 4; ++j) {
            float* row = Yb + (size_t)(o0 + q * 64 + ty * 4 + j) * LSEQ + t0;
            float4 v0 = *(const float4*)(row + tx * 4);
            float4 v1 = *(const float4*)(row + 64 + tx * 4);
            *(float4*)(row + tx * 4) =
                make_float4(q8(__fadd_rn(acc[0][0][q][j], v0.x)),
                            q8(__fadd_rn(acc[0][1][q][j], v0.y)),
                            q8(__fadd_rn(acc[0][2][q][j], v0.z)),
                            q8(__fadd_rn(acc[0][3][q][j], v0.w)));
            *(float4*)(row + 64 + tx * 4) =
                make_float4(q8(__fadd_rn(acc[1][0][q][j], v1.x)),
                            q8(__fadd_rn(acc[1][1][q][j], v1.y)),
                            q8(__fadd_rn(acc[1][2][q][j], v1.z)),
                            q8(__fadd_rn(acc[1][3][q][j], v1.w)));
        }
}

extern "C" void kernel_launch(void* const* d_in, const int* in_sizes, int n_in,
                              void* d_out, int out_size, void* d_ws, size_t ws_size,
                              hipStream_t stream) {
    const float* u = (const float*)d_in[0];   // (32, 512, 512)
    const float* A = (const float*)d_in[1];   // (512,)
    const float* B = (const float*)d_in[2];   // (512, 512)
    const float* C = (const float*)d_in[3];   // (512, 512)
    const float* D = (const float*)d_in[4];   // (512, 512)

    float* ws  = (float*)d_ws;
    float* Aq  = ws;                    // 512
    float* Bqt = Aq + 512;              // 262144  [d][n]
    float* Cqt = Bqt + 262144;          // 262144  [n][o]
    float* Dqt = Cqt + 262144;          // 262144  [d][o]
    float* R   = Dqt + 262144;          // 8388608 [b][t][n]
    float* S   = R + 8388608;           // 8388608 [b][n][t]
    float* Y   = (float*)d_out;         // 8388608 [b][o][t] (also Pd scratch)

    quantBA<<<dim3(16, 16), 256, 0, stream>>>(B, A, Bqt, Aq);
    fused_RqCD<<<1024, 256, 0, stream>>>(u, Bqt, C, D, R, Cqt, Dqt);
    fused_Drec<<<768, 256, 0, stream>>>(u, Dqt, R, Aq, Y, S);
    gemm_YC<<<dim3(4, 4, 32), 256, 0, stream>>>(S, Cqt, Y);
}